// Round 13
// baseline (661.914 us; speedup 1.0000x reference)
//
#include <hip/hip_runtime.h>
#include <stdint.h>
#include <stddef.h>

typedef short bf16x8 __attribute__((ext_vector_type(8)));
typedef float f32x4  __attribute__((ext_vector_type(4)));
typedef unsigned short ushort_t;

#define H_ 256
#define W_ 448
#define HP_ 258
#define WP_ 450
#define NPIX (H_*W_)
#define PPLANE (HP_*WP_)

// ---------------- workspace layout (bytes) ----------------
#define XPAD_OFF 0ull
#define XPAD_CB_STRIDE ((size_t)2*PPLANE*16)      // 3,715,200 per ci-block of 8
#define XPAD_CB_STRIDE32 (3715200u)
#define XPAD_SIZE ((size_t)64*XPAD_CB_STRIDE)     // 237,772,800
#define FPAD_OFF (XPAD_OFF + XPAD_SIZE)
#define FPAD_SIZE ((size_t)2*PPLANE*16)           // 3,715,200
#define WT_OFF   (FPAD_OFF + FPAD_SIZE)
#define WT_SIZE  ((size_t)256*9*512*2)            // 2,359,296
#define WTF_OFF  (WT_OFF + WT_SIZE)
#define WTF_SIZE ((size_t)256*128*2)              // 65,536
#define WS_NEEDED (WTF_OFF + WTF_SIZE)

__device__ __forceinline__ ushort_t bf16r(float f){
  union { float f; uint32_t u; } c; c.f = f;
  uint32_t u = c.u;
  return (ushort_t)((u + 0x7FFFu + ((u >> 16) & 1u)) >> 16);
}

// ---------------- prep: features -> padded NHWC-blocked bf16 ----------------
__global__ void prep_x(const float* __restrict__ feat, uint8_t* __restrict__ ws){
  int blk = blockIdx.x;
  int yp = blk % HP_;
  int t  = blk / HP_;
  int b  = t & 1;
  int cb = t >> 1;
  uint8_t* dst = ws + XPAD_OFF + (size_t)(cb*2 + b)*((size_t)PPLANE*16) + (size_t)yp*WP_*16;
  bool inrow = (yp >= 1 && yp <= H_);
  const float* src0 = feat + ((size_t)b*512 + (size_t)cb*8)*((size_t)H_*W_) + (size_t)(yp-1)*W_;
  for(int xp = threadIdx.x; xp < WP_; xp += blockDim.x){
    union { ushort_t u[8]; uint4 q; } v;
    if(inrow && xp >= 1 && xp <= W_){
      int x = xp - 1;
      #pragma unroll
      for(int r = 0; r < 8; r++) v.u[r] = bf16r(src0[(size_t)r*H_*W_ + x]);
    } else {
      v.q = make_uint4(0,0,0,0);
    }
    *(uint4*)(dst + (size_t)xp*16) = v.q;
  }
}

// ---------------- prep: flows -> padded NHWC bf16 (8 ch records) ----------------
__global__ void prep_f(const float* __restrict__ init_flow, const float* __restrict__ flow_fix,
                       uint8_t* __restrict__ ws){
  int blk = blockIdx.x;
  int yp = blk % HP_;
  int b  = blk / HP_;
  uint8_t* dst = ws + FPAD_OFF + ((size_t)b*PPLANE + (size_t)yp*WP_)*16;
  for(int xp = threadIdx.x; xp < WP_; xp += blockDim.x){
    union { ushort_t u[8]; uint4 q; } v;
    if(yp >= 1 && yp <= H_ && xp >= 1 && xp <= W_){
      int y = yp - 1, x = xp - 1;
      #pragma unroll
      for(int r = 0; r < 4; r++) v.u[r]   = bf16r(init_flow[(((size_t)b*4 + r)*H_ + y)*W_ + x]);
      #pragma unroll
      for(int r = 0; r < 4; r++) v.u[4+r] = bf16r(flow_fix [(((size_t)b*4 + r)*H_ + y)*W_ + x]);
    } else {
      v.q = make_uint4(0,0,0,0);
    }
    *(uint4*)(dst + (size_t)xp*16) = v.q;
  }
}

// ---------------- prep: weights -> bf16, K-contiguous layouts ----------------
__global__ void prep_w(const float* __restrict__ w1, uint8_t* __restrict__ ws){
  int idx = blockIdx.x*256 + threadIdx.x;
  ushort_t* wt  = (ushort_t*)(ws + WT_OFF);
  ushort_t* wtf = (ushort_t*)(ws + WTF_OFF);
  if(idx < 256*9*512){
    int co  = idx / (9*512);
    int rem = idx % (9*512);
    int s   = rem / 512;
    int ci  = rem % 512;
    float v = w1[((size_t)co*520 + 8 + ci)*9 + s];
    wt[((size_t)co*9 + s)*512 + ci] = bf16r(v);
  } else {
    int i2 = idx - 256*9*512;
    if(i2 < 256*128){
      int co = i2 >> 7;
      int k  = i2 & 127;
      float v = 0.f;
      if(k < 64){ int s = k >> 3, c = k & 7; v = w1[((size_t)co*520 + c)*9 + s]; }
      else if(k < 72){ int c = k - 64;       v = w1[((size_t)co*520 + c)*9 + 8]; }
      wtf[co*128 + k] = bf16r(v);
    }
  }
}

// ---------------- fused conv3x3 + PReLU + conv1x1 + softmax + merge ----------------
// BM=224 (half-row tiles, no y-crossing), BN=256, BK=64, 8 waves (2Mx4N),
// wave tile 112x64, acc[7][4]. Halo strips + B 3-buffer rotation. Per-wave
// software pipeline, ONE barrier per step (R12). THIS ROUND: parity-staggered
// phase bodies — even waves read-then-MFMA, odd waves MFMA-then-read, breaking
// the post-barrier read convoy so MFMA and LDS pipes overlap across waves.
#define BBASE  65536u
#define MASK_OFF 57344u
#define W2_OFF 98304u
#define SMEM_TOTAL 163840

__device__ __forceinline__ void gload16(const uint8_t* g, uint8_t* l){
  __builtin_amdgcn_global_load_lds((const __attribute__((address_space(1))) uint32_t*)g,
                                   (__attribute__((address_space(3))) uint32_t*)l, 16, 0, 0);
}
__device__ __forceinline__ void bar(){
  asm volatile("" ::: "memory");
  __builtin_amdgcn_s_barrier();
  asm volatile("" ::: "memory");
}
__device__ __forceinline__ void bar_lds(){
  asm volatile("s_waitcnt lgkmcnt(0)" ::: "memory");
  __builtin_amdgcn_s_barrier();
  asm volatile("" ::: "memory");
}

__launch_bounds__(512, 2)
__global__ void mega(const uint8_t* __restrict__ ws, const float* __restrict__ w2,
                     const float* __restrict__ b1, const float* __restrict__ pw,
                     const float* __restrict__ b2,
                     const float* __restrict__ init_flow, const float* __restrict__ flow_fix,
                     float* __restrict__ out){
  __shared__ uint8_t smem[SMEM_TOTAL];
  const int tid = threadIdx.x;
  const int l   = tid & 63;
  const int w   = tid >> 6;
  // T1: XCD-aware bijective swizzle (1024 = 8 * 128)
  const int blk0 = blockIdx.x;
  const int blk  = (blk0 & 7)*128 + (blk0 >> 3);
  const int b   = blk / 512;
  const int wi  = blk % 512;
  const int y0  = wi >> 1;
  const int x0  = (wi & 1)*224;

  const uint8_t* xpad = ws + XPAD_OFF;
  const uint8_t* fpad = ws + FPAD_OFF;
  const uint8_t* wt   = ws + WT_OFF;
  const uint8_t* wtf  = ws + WTF_OFF;

  // --- per-lane staging precompute (dest D = q*8192 + tid*16; swizzle keeps rec) ---
  const int base72 = (b*PPLANE + (y0 + 1)*WP_ + (x0 + 1))*16;   // pixel m=0, tap (1,1)
  uint32_t soff[4]; int f72rel[4], f73rel[4];
  #pragma unroll
  for(int q = 0; q < 4; q++){
    uint32_t D = (uint32_t)(q*8192 + tid*16);
    uint32_t rec  = D >> 7;                                 // strip record / pixel m
    uint32_t slot = ((D >> 4) & 7u) ^ (rec & 7u);           // 8ch sub-block within K=64
    soff[q] = slot*XPAD_CB_STRIDE32 + rec*16u;
    if(rec < 224u){
      int dyq = (int)slot/3, dxq = (int)slot - dyq*3;
      f72rel[q] = ((int)rec + (dyq - 1)*WP_ + (dxq - 1))*16;
    } else f72rel[q] = -base72;
    if(rec < 224u && slot == 0u) f73rel[q] = ((int)rec + WP_ + 1)*16;
    else                          f73rel[q] = -base72;      // fpad record 0 = zeros
  }
  uint32_t boff2[4], bfl[4];
  #pragma unroll
  for(int r = 0; r < 4; r++){
    uint32_t D = (uint32_t)(r*8192 + tid*16);
    uint32_t L = D ^ (((D >> 7) & 7u) << 4);
    uint32_t co = L >> 7, cib = L & 127u;
    boff2[r] = co*9216u + cib;
    bfl[r]   = co*256u + cib;
  }

  // fragment-read constants
  const int wave_m = w >> 2, wave_n = w & 3;
  const bool rf = ((w & 1) == 0);          // parity: even waves read-first
  const uint32_t koff = ((uint32_t)(l >> 4))*16u;
  const uint32_t swB  = ((uint32_t)(l & 7)) << 4;
  const uint32_t rb0  = (uint32_t)(wave_m*112 + (l & 15));
  const uint32_t rowBb = ((uint32_t)(wave_n*64 + (l & 15)))*128u;

  const f32x4 zero4 = {0.f, 0.f, 0.f, 0.f};
  f32x4 acc[7][4];
  #pragma unroll
  for(int i = 0; i < 7; i++)
    #pragma unroll
    for(int j = 0; j < 4; j++) acc[i][j] = zero4;

  // --- staging (wave-uniform LDS base + lane*16; 4 loads/thread always) ---
  auto stStrip = [&](int g2){                // g2 = unit index 0..23 -> buf g2&1
    int kk2 = g2/3, dy2 = g2 - kk2*3;
    uint32_t base = (uint32_t)(kk2*8)*XPAD_CB_STRIDE32 + (uint32_t)(b*(PPLANE*16))
                  + (uint32_t)(((y0 + dy2)*WP_ + x0)*16);
    uint8_t* la = smem + (uint32_t)(g2 & 1)*32768u + (uint32_t)(w*1024);
    #pragma unroll
    for(int q = 0; q < 4; q++) gload16(xpad + (base + soff[q]), la + q*8192);
  };
  auto stFlow = [&](int which){              // which 0/1 -> strip buf which
    uint8_t* la = smem + (uint32_t)which*32768u + (uint32_t)(w*1024);
    #pragma unroll
    for(int q = 0; q < 4; q++){
      int rel = which ? f73rel[q] : f72rel[q];
      gload16(fpad + (uint32_t)(base72 + rel), la + q*8192);
    }
  };
  auto stB = [&](int s2, int dstb){
    uint8_t* lb = smem + BBASE + (uint32_t)dstb*32768u + (uint32_t)(w*1024);
    if(s2 < 72){
      int kk2 = s2/9, tap = s2 - kk2*9;
      uint32_t stepB = (uint32_t)(tap*1024 + kk2*128);
      #pragma unroll
      for(int r = 0; r < 4; r++) gload16(wt + (boff2[r] + stepB), lb + r*8192);
    } else {
      uint32_t add = (s2 == 72) ? 0u : 128u;
      #pragma unroll
      for(int r = 0; r < 4; r++) gload16(wtf + (bfl[r] + add), lb + r*8192);
    }
  };
  auto stA_next = [&](int s2){               // stage A for unit s2/3 + 1
    int nxt = s2/3 + 1;
    if(nxt < 24)       stStrip(nxt);
    else if(nxt == 24) stFlow(0);
    else               stFlow(1);
  };

  // fragment readers
  auto rdA = [&](const uint8_t* Ab_, uint32_t rec, uint32_t kc64) -> bf16x8 {
    return *(const bf16x8*)(Ab_ + ((rec << 7) + ((kc64 + koff) ^ ((rec & 7u) << 4))));
  };
  auto rdB = [&](const uint8_t* Bb_, int ni, uint32_t kc64) -> bf16x8 {
    return *(const bf16x8*)(Bb_ + (rowBb + (uint32_t)(ni*2048) + ((kc64 + koff) ^ swB)));
  };

  bf16x8 avX[4], avY[4], bv0[4], bv1[4];

  // prologue: B0->Bbuf0, strip0->Abuf0, B1->Bbuf1; retire B0+strip0 (leave B1)
  stB(0, 0);
  stStrip(0);
  stB(1, 1);
  asm volatile("s_waitcnt vmcnt(4)" ::: "memory");
  bar();
  // pre-read step0 ph0 fragments
  #pragma unroll
  for(int mi = 0; mi < 4; mi++) avX[mi] = rdA(smem, rb0 + (uint32_t)(mi*16), 0u);
  #pragma unroll
  for(int ni = 0; ni < 4; ni++) bv0[ni] = rdB(smem + BBASE, ni, 0u);

  #pragma unroll 1
  for(int s = 0; s < 74; s++){
    const int gbuf = (s < 72) ? ((s/3) & 1) : (s - 72);
    const uint8_t* Ab = smem + (uint32_t)gbuf*32768u;
    const uint8_t* Bb = smem + BBASE + (uint32_t)(s % 3)*32768u;
    const uint32_t rdx = (s < 72) ? (uint32_t)(s % 3) : 0u;

    // per-phase read groups (operands for the NEXT phase)
    auto RD0 = [&]{   // avY r0-3 kc1 + bv1 (for ph1)
      #pragma unroll
      for(int mi = 0; mi < 4; mi++) avY[mi] = rdA(Ab, rb0 + (uint32_t)(mi*16) + rdx, 64u);
      #pragma unroll
      for(int ni = 0; ni < 4; ni++) bv1[ni] = rdB(Bb, ni, 64u);
    };
    auto RD1 = [&]{   // avX r4-6 kc0 (for ph2)
      #pragma unroll
      for(int mi = 0; mi < 3; mi++) avX[mi] = rdA(Ab, rb0 + (uint32_t)((mi+4)*16) + rdx, 0u);
    };
    auto RD2 = [&]{   // avY r4-6 kc1 (for ph3)
      #pragma unroll
      for(int mi = 0; mi < 3; mi++) avY[mi] = rdA(Ab, rb0 + (uint32_t)((mi+4)*16) + rdx, 64u);
    };
    auto RD3 = [&]{   // next step's avX r0-3 kc0 + bv0 (for next ph0)
      if(s < 73){
        const int s1 = s + 1;
        const int gbuf1 = (s1 < 72) ? ((s1/3) & 1) : (s1 - 72);
        const uint8_t* Ab1 = smem + (uint32_t)gbuf1*32768u;
        const uint8_t* Bb1 = smem + BBASE + (uint32_t)(s1 % 3)*32768u;
        const uint32_t rdx1 = (s1 < 72) ? (uint32_t)(s1 % 3) : 0u;
        #pragma unroll
        for(int mi = 0; mi < 4; mi++) avX[mi] = rdA(Ab1, rb0 + (uint32_t)(mi*16) + rdx1, 0u);
        #pragma unroll
        for(int ni = 0; ni < 4; ni++) bv0[ni] = rdB(Bb1, ni, 0u);
      }
    };
    auto MM0 = [&]{
      __builtin_amdgcn_s_setprio(1);
      #pragma unroll
      for(int ni = 0; ni < 4; ni++)
        #pragma unroll
        for(int mi = 0; mi < 4; mi++)
          acc[mi][ni] = __builtin_amdgcn_mfma_f32_16x16x32_bf16(avX[mi], bv0[ni], acc[mi][ni], 0, 0, 0);
      __builtin_amdgcn_s_setprio(0);
    };
    auto MM1 = [&]{
      __builtin_amdgcn_s_setprio(1);
      #pragma unroll
      for(int ni = 0; ni < 4; ni++)
        #pragma unroll
        for(int mi = 0; mi < 4; mi++)
          acc[mi][ni] = __builtin_amdgcn_mfma_f32_16x16x32_bf16(avY[mi], bv1[ni], acc[mi][ni], 0, 0, 0);
      __builtin_amdgcn_s_setprio(0);
    };
    auto MM2 = [&]{
      __builtin_amdgcn_s_setprio(1);
      #pragma unroll
      for(int ni = 0; ni < 4; ni++)
        #pragma unroll
        for(int mi = 0; mi < 3; mi++)
          acc[mi+4][ni] = __builtin_amdgcn_mfma_f32_16x16x32_bf16(avX[mi], bv0[ni], acc[mi+4][ni], 0, 0, 0);
      __builtin_amdgcn_s_setprio(0);
    };
    auto MM3 = [&]{
      __builtin_amdgcn_s_setprio(1);
      #pragma unroll
      for(int ni = 0; ni < 4; ni++)
        #pragma unroll
        for(int mi = 0; mi < 3; mi++)
          acc[mi+4][ni] = __builtin_amdgcn_mfma_f32_16x16x32_bf16(avY[mi], bv1[ni], acc[mi+4][ni], 0, 0, 0);
      __builtin_amdgcn_s_setprio(0);
    };

    // ---- ph0 ----
    if(rf) RD0();
    if(s < 72) stB(s + 2, (s + 2) % 3);
    if((s % 3) == 0 && s < 73) stA_next(s);
    MM0();
    if(!rf) RD0();
    // ---- ph1 ----
    if(rf) RD1();
    MM1();
    if(!rf) RD1();
    // ---- ph2 ----
    if(rf) RD2();
    MM2();
    if(!rf) RD2();
    if((s % 3) == 0){
      if(s < 72) asm volatile("s_waitcnt vmcnt(8)" ::: "memory");
      else       asm volatile("s_waitcnt vmcnt(0)" ::: "memory");
    } else {
      asm volatile("s_waitcnt vmcnt(4)" ::: "memory");
    }
    bar();     // the ONLY barrier per step
    // ---- ph3 ----
    if(rf) RD3();
    MM3();
    if(!rf) RD3();
  }

  // --- stage W2 (fp32 -> bf16) into LDS @W2_OFF, 512B rows, XOR-swizzled ---
  for(int e2 = tid; e2 < 48*256; e2 += 512){
    int row = e2 >> 8, k = e2 & 255;
    float f = (row < 36) ? w2[row*256 + k] : 0.f;
    uint32_t phys = ((uint32_t)(row*512 + k*2)) ^ (((uint32_t)(row & 7)) << 4);
    *(ushort_t*)(smem + W2_OFF + phys) = bf16r(f);
  }

  // --- epilogue: two passes of 112 pixels each ---
  #pragma unroll
  for(int pass = 0; pass < 2; pass++){
    if(pass) bar();
    if(wave_m == pass){
      #pragma unroll
      for(int ni = 0; ni < 4; ni++){
        int co = wave_n*64 + ni*16 + (l & 15);
        float bb1 = b1[co];
        float pp = pw[co];
        #pragma unroll
        for(int mi = 0; mi < 7; mi++){
          #pragma unroll
          for(int j = 0; j < 4; j++){
            float v = acc[mi][ni][j] + bb1;
            v = (v < 0.f) ? v*pp : v;
            int px = mi*16 + ((l >> 4) << 2) + j;     // 0..111
            uint32_t phys = ((uint32_t)(px*512 + co*2)) ^ (((uint32_t)(px & 7)) << 4);
            *(ushort_t*)(smem + phys) = bf16r(v);
          }
        }
      }
    }
    bar_lds();

    // mask GEMM: waves 0-6 -> px rows [16w,16w+16), N=48 (36 valid), K=256
    f32x4 acc2[3];
    #pragma unroll
    for(int ni = 0; ni < 3; ni++) acc2[ni] = zero4;
    if(w < 7){
      const uint32_t rowX = ((uint32_t)(16*w + (l & 15)))*512u;
      #pragma unroll
      for(int kq = 0; kq < 8; kq++){
        bf16x8 avx = *(const bf16x8*)(smem + ((rowX + (uint32_t)(kq*64) + koff) ^ swB));
        #pragma unroll
        for(int ni = 0; ni < 3; ni++){
          uint32_t rowW = ((uint32_t)(ni*16 + (l & 15)))*512u;
          bf16x8 bvx = *(const bf16x8*)(smem + W2_OFF + ((rowW + (uint32_t)(kq*64) + koff) ^ swB));
          acc2[ni] = __builtin_amdgcn_mfma_f32_16x16x32_bf16(avx, bvx, acc2[ni], 0, 0, 0);
        }
      }
    }
    bar_lds();   // all x reads done before mask overwrites smem regions
    if(w < 7){
      float* ml = (float*)(smem + MASK_OFF);
      #pragma unroll
      for(int ni = 0; ni < 3; ni++){
        int co2 = ni*16 + (l & 15);
        float bb2 = b2[co2 < 36 ? co2 : 35];
        #pragma unroll
        for(int j = 0; j < 4; j++){
          int px = 16*w + ((l >> 4) << 2) + j;
          ml[px*48 + co2] = acc2[ni][j] + bb2;
        }
      }
    }
    bar_lds();

    // softmax(2x18) + unfold-merge, 4 threads per pixel (112 px/pass -> 448 tasks)
    if(tid < 448){
      int px = tid >> 2;
      int hh = (tid >> 1) & 1;
      int c  = tid & 1;
      const float* ml = (const float*)(smem + MASK_OFF) + px*48 + hh*18;
      float mx = ml[0];
      #pragma unroll
      for(int k = 1; k < 18; k++) mx = fmaxf(mx, ml[k]);
      float e[18]; float sum = 0.f;
      #pragma unroll
      for(int k = 0; k < 18; k++){ e[k] = __expf(ml[k] - mx); sum += e[k]; }
      float inv = 1.f / sum;
      int x = x0 + pass*112 + px;
      int y = y0;
      const float* fi = init_flow + (size_t)(b*4 + 2*hh + c)*NPIX;
      const float* ff = flow_fix  + (size_t)(b*4 + 2*hh + c)*NPIX;
      float o = 0.f;
      #pragma unroll
      for(int s = 0; s < 9; s++){
        int yy = y + (s/3) - 1, xx = x + (s%3) - 1;
        if(yy >= 0 && yy < H_ && xx >= 0 && xx < W_){
          int idx = yy*W_ + xx;
          o += e[s]*fi[idx] + e[9+s]*ff[idx];
        }
      }
      out[(size_t)((b + 2*hh)*2 + c)*NPIX + y*W_ + x] = o * inv;
    }
  }
}

// ---------------- launcher ----------------
extern "C" void kernel_launch(void* const* d_in, const int* in_sizes, int n_in,
                              void* d_out, int out_size, void* d_ws, size_t ws_size,
                              hipStream_t stream) {
  const float* feature   = (const float*)d_in[0];
  const float* init_flow = (const float*)d_in[1];
  const float* flow_fix  = (const float*)d_in[2];
  const float* w1        = (const float*)d_in[3];
  const float* b1        = (const float*)d_in[4];
  const float* prelu_w   = (const float*)d_in[5];
  const float* w2        = (const float*)d_in[6];
  const float* b2        = (const float*)d_in[7];
  float* out = (float*)d_out;
  uint8_t* ws = (uint8_t*)d_ws;

  if(ws_size < WS_NEEDED) return;  // insufficient workspace -> fail visibly

  prep_x<<<64*2*HP_, 256, 0, stream>>>(feature, ws);
  prep_f<<<2*HP_,    256, 0, stream>>>(init_flow, flow_fix, ws);
  prep_w<<<4736,     256, 0, stream>>>(w1, ws);
  mega<<<1024, 512, 0, stream>>>(ws, w2, b1, prelu_w, b2, init_flow, flow_fix, out);
}

// Round 14
// 600.248 us; speedup vs baseline: 1.1027x; 1.1027x over previous
//
#include <hip/hip_runtime.h>
#include <stdint.h>
#include <stddef.h>

typedef short bf16x8 __attribute__((ext_vector_type(8)));
typedef float f32x4  __attribute__((ext_vector_type(4)));
typedef unsigned short ushort_t;

#define H_ 256
#define W_ 448
#define HP_ 258
#define WP_ 450
#define NPIX (H_*W_)
#define PPLANE (HP_*WP_)

// ---------------- workspace layout (bytes) ----------------
#define XPAD_OFF 0ull
#define XPAD_CB_STRIDE ((size_t)2*PPLANE*16)      // 3,715,200 per ci-block of 8
#define XPAD_CB_STRIDE32 (3715200u)
#define XPAD_SIZE ((size_t)64*XPAD_CB_STRIDE)     // 237,772,800
#define FPAD_OFF (XPAD_OFF + XPAD_SIZE)
#define FPAD_SIZE ((size_t)2*PPLANE*16)           // 3,715,200
#define WT_OFF   (FPAD_OFF + FPAD_SIZE)
#define WT_SIZE  ((size_t)256*9*512*2)            // 2,359,296
#define WTF_OFF  (WT_OFF + WT_SIZE)
#define WTF_SIZE ((size_t)256*128*2)              // 65,536
#define WS_NEEDED (WTF_OFF + WTF_SIZE)

__device__ __forceinline__ ushort_t bf16r(float f){
  union { float f; uint32_t u; } c; c.f = f;
  uint32_t u = c.u;
  return (ushort_t)((u + 0x7FFFu + ((u >> 16) & 1u)) >> 16);
}

// ---------------- prep: features -> padded NHWC-blocked bf16 ----------------
__global__ void prep_x(const float* __restrict__ feat, uint8_t* __restrict__ ws){
  int blk = blockIdx.x;
  int yp = blk % HP_;
  int t  = blk / HP_;
  int b  = t & 1;
  int cb = t >> 1;
  uint8_t* dst = ws + XPAD_OFF + (size_t)(cb*2 + b)*((size_t)PPLANE*16) + (size_t)yp*WP_*16;
  bool inrow = (yp >= 1 && yp <= H_);
  const float* src0 = feat + ((size_t)b*512 + (size_t)cb*8)*((size_t)H_*W_) + (size_t)(yp-1)*W_;
  for(int xp = threadIdx.x; xp < WP_; xp += blockDim.x){
    union { ushort_t u[8]; uint4 q; } v;
    if(inrow && xp >= 1 && xp <= W_){
      int x = xp - 1;
      #pragma unroll
      for(int r = 0; r < 8; r++) v.u[r] = bf16r(src0[(size_t)r*H_*W_ + x]);
    } else {
      v.q = make_uint4(0,0,0,0);
    }
    *(uint4*)(dst + (size_t)xp*16) = v.q;
  }
}

// ---------------- prep: flows -> padded NHWC bf16 (8 ch records) ----------------
__global__ void prep_f(const float* __restrict__ init_flow, const float* __restrict__ flow_fix,
                       uint8_t* __restrict__ ws){
  int blk = blockIdx.x;
  int yp = blk % HP_;
  int b  = blk / HP_;
  uint8_t* dst = ws + FPAD_OFF + ((size_t)b*PPLANE + (size_t)yp*WP_)*16;
  for(int xp = threadIdx.x; xp < WP_; xp += blockDim.x){
    union { ushort_t u[8]; uint4 q; } v;
    if(yp >= 1 && yp <= H_ && xp >= 1 && xp <= W_){
      int y = yp - 1, x = xp - 1;
      #pragma unroll
      for(int r = 0; r < 4; r++) v.u[r]   = bf16r(init_flow[(((size_t)b*4 + r)*H_ + y)*W_ + x]);
      #pragma unroll
      for(int r = 0; r < 4; r++) v.u[4+r] = bf16r(flow_fix [(((size_t)b*4 + r)*H_ + y)*W_ + x]);
    } else {
      v.q = make_uint4(0,0,0,0);
    }
    *(uint4*)(dst + (size_t)xp*16) = v.q;
  }
}

// ---------------- prep: weights -> bf16, K-contiguous layouts ----------------
__global__ void prep_w(const float* __restrict__ w1, uint8_t* __restrict__ ws){
  int idx = blockIdx.x*256 + threadIdx.x;
  ushort_t* wt  = (ushort_t*)(ws + WT_OFF);
  ushort_t* wtf = (ushort_t*)(ws + WTF_OFF);
  if(idx < 256*9*512){
    int co  = idx / (9*512);
    int rem = idx % (9*512);
    int s   = rem / 512;
    int ci  = rem % 512;
    float v = w1[((size_t)co*520 + 8 + ci)*9 + s];
    wt[((size_t)co*9 + s)*512 + ci] = bf16r(v);
  } else {
    int i2 = idx - 256*9*512;
    if(i2 < 256*128){
      int co = i2 >> 7;
      int k  = i2 & 127;
      float v = 0.f;
      if(k < 64){ int s = k >> 3, c = k & 7; v = w1[((size_t)co*520 + c)*9 + s]; }
      else if(k < 72){ int c = k - 64;       v = w1[((size_t)co*520 + c)*9 + 8]; }
      wtf[co*128 + k] = bf16r(v);
    }
  }
}

// ---------------- fused conv3x3 + PReLU + conv1x1 + softmax + merge ----------------
// BM=224 (half-row tiles, no y-crossing), BN=256, BK=64, 8 waves (2Mx4N),
// wave tile 112x64, acc[7][4]. Halo strips + B 3-buffer rotation. Per-wave
// software pipeline, ONE barrier per step (R12). THIS ROUND: fragment-read
// addresses reduced to 4 per-step base registers + compile-time immediate
// offsets (rec&7 invariant across mi since mi*16 == 0 mod 8; kc1 col = kc0^64).
#define BBASE  65536u
#define MASK_OFF 57344u
#define W2_OFF 98304u
#define SMEM_TOTAL 163840

__device__ __forceinline__ void gload16(const uint8_t* g, uint8_t* l){
  __builtin_amdgcn_global_load_lds((const __attribute__((address_space(1))) uint32_t*)g,
                                   (__attribute__((address_space(3))) uint32_t*)l, 16, 0, 0);
}
__device__ __forceinline__ void bar(){
  asm volatile("" ::: "memory");
  __builtin_amdgcn_s_barrier();
  asm volatile("" ::: "memory");
}
__device__ __forceinline__ void bar_lds(){
  asm volatile("s_waitcnt lgkmcnt(0)" ::: "memory");
  __builtin_amdgcn_s_barrier();
  asm volatile("" ::: "memory");
}

__launch_bounds__(512, 2)
__global__ void mega(const uint8_t* __restrict__ ws, const float* __restrict__ w2,
                     const float* __restrict__ b1, const float* __restrict__ pw,
                     const float* __restrict__ b2,
                     const float* __restrict__ init_flow, const float* __restrict__ flow_fix,
                     float* __restrict__ out){
  __shared__ uint8_t smem[SMEM_TOTAL];
  const int tid = threadIdx.x;
  const int l   = tid & 63;
  const int w   = tid >> 6;
  // T1: XCD-aware bijective swizzle (1024 = 8 * 128)
  const int blk0 = blockIdx.x;
  const int blk  = (blk0 & 7)*128 + (blk0 >> 3);
  const int b   = blk / 512;
  const int wi  = blk % 512;
  const int y0  = wi >> 1;
  const int x0  = (wi & 1)*224;

  const uint8_t* xpad = ws + XPAD_OFF;
  const uint8_t* fpad = ws + FPAD_OFF;
  const uint8_t* wt   = ws + WT_OFF;
  const uint8_t* wtf  = ws + WTF_OFF;

  // --- per-lane staging precompute (dest D = q*8192 + tid*16; swizzle keeps rec) ---
  const int base72 = (b*PPLANE + (y0 + 1)*WP_ + (x0 + 1))*16;   // pixel m=0, tap (1,1)
  uint32_t soff[4]; int f72rel[4], f73rel[4];
  #pragma unroll
  for(int q = 0; q < 4; q++){
    uint32_t D = (uint32_t)(q*8192 + tid*16);
    uint32_t rec  = D >> 7;                                 // strip record / pixel m
    uint32_t slot = ((D >> 4) & 7u) ^ (rec & 7u);           // 8ch sub-block within K=64
    soff[q] = slot*XPAD_CB_STRIDE32 + rec*16u;
    if(rec < 224u){
      int dyq = (int)slot/3, dxq = (int)slot - dyq*3;
      f72rel[q] = ((int)rec + (dyq - 1)*WP_ + (dxq - 1))*16;
    } else f72rel[q] = -base72;
    if(rec < 224u && slot == 0u) f73rel[q] = ((int)rec + WP_ + 1)*16;
    else                          f73rel[q] = -base72;      // fpad record 0 = zeros
  }
  uint32_t boff2[4], bfl[4];
  #pragma unroll
  for(int r = 0; r < 4; r++){
    uint32_t D = (uint32_t)(r*8192 + tid*16);
    uint32_t L = D ^ (((D >> 7) & 7u) << 4);
    uint32_t co = L >> 7, cib = L & 127u;
    boff2[r] = co*9216u + cib;
    bfl[r]   = co*256u + cib;
  }

  // fragment-read constants
  const int wave_m = w >> 2, wave_n = w & 3;
  const uint32_t koff = ((uint32_t)(l >> 4))*16u;
  const uint32_t swB  = ((uint32_t)(l & 7)) << 4;
  const uint32_t rb0  = (uint32_t)(wave_m*112 + (l & 15));
  const uint32_t rowBb = ((uint32_t)(wave_n*64 + (l & 15)))*128u;

  // per-step read bases (precomputed per-lane scalars; selected per step)
  // A kc0 byte offset within buffer = ((rb0+r)<<7) + (koff ^ (((rb0+r)&7)<<4));
  // kc1 = kc0 ^ 64; row-groups mi / mi+4 are pure immediate offsets (mi*2048).
  const uint32_t bA0_0 = ((rb0 + 0u) << 7) + (koff ^ (((rb0 + 0u) & 7u) << 4));
  const uint32_t bA0_1 = ((rb0 + 1u) << 7) + (koff ^ (((rb0 + 1u) & 7u) << 4));
  const uint32_t bA0_2 = ((rb0 + 2u) << 7) + (koff ^ (((rb0 + 2u) & 7u) << 4));
  const uint32_t bB0   = BBASE + rowBb + (koff ^ swB);

  const f32x4 zero4 = {0.f, 0.f, 0.f, 0.f};
  f32x4 acc[7][4];
  #pragma unroll
  for(int i = 0; i < 7; i++)
    #pragma unroll
    for(int j = 0; j < 4; j++) acc[i][j] = zero4;

  // --- staging (wave-uniform LDS base + lane*16; 4 loads/thread always) ---
  auto stStrip = [&](int g2){                // g2 = unit index 0..23 -> buf g2&1
    int kk2 = g2/3, dy2 = g2 - kk2*3;
    uint32_t base = (uint32_t)(kk2*8)*XPAD_CB_STRIDE32 + (uint32_t)(b*(PPLANE*16))
                  + (uint32_t)(((y0 + dy2)*WP_ + x0)*16);
    uint8_t* la = smem + (uint32_t)(g2 & 1)*32768u + (uint32_t)(w*1024);
    #pragma unroll
    for(int q = 0; q < 4; q++) gload16(xpad + (base + soff[q]), la + q*8192);
  };
  auto stFlow = [&](int which){              // which 0/1 -> strip buf which
    uint8_t* la = smem + (uint32_t)which*32768u + (uint32_t)(w*1024);
    #pragma unroll
    for(int q = 0; q < 4; q++){
      int rel = which ? f73rel[q] : f72rel[q];
      gload16(fpad + (uint32_t)(base72 + rel), la + q*8192);
    }
  };
  auto stB = [&](int s2, int dstb){
    uint8_t* lb = smem + BBASE + (uint32_t)dstb*32768u + (uint32_t)(w*1024);
    if(s2 < 72){
      int kk2 = s2/9, tap = s2 - kk2*9;
      uint32_t stepB = (uint32_t)(tap*1024 + kk2*128);
      #pragma unroll
      for(int r = 0; r < 4; r++) gload16(wt + (boff2[r] + stepB), lb + r*8192);
    } else {
      uint32_t add = (s2 == 72) ? 0u : 128u;
      #pragma unroll
      for(int r = 0; r < 4; r++) gload16(wtf + (bfl[r] + add), lb + r*8192);
    }
  };
  auto stA_next = [&](int s2){               // stage A for unit s2/3 + 1
    int nxt = s2/3 + 1;
    if(nxt < 24)       stStrip(nxt);
    else if(nxt == 24) stFlow(0);
    else               stFlow(1);
  };

  bf16x8 avX[4], avY[4], bv0[4], bv1[4];

  // prologue: B0->Bbuf0, strip0->Abuf0, B1->Bbuf1; retire B0+strip0 (leave B1)
  stB(0, 0);
  stStrip(0);
  stB(1, 1);
  asm volatile("s_waitcnt vmcnt(4)" ::: "memory");
  bar();
  // pre-read step0 ph0 fragments (gbuf=0, rdx=0, Bbuf=0)
  #pragma unroll
  for(int mi = 0; mi < 4; mi++)
    avX[mi] = *(const bf16x8*)(smem + bA0_0 + (uint32_t)(mi*2048));
  #pragma unroll
  for(int ni = 0; ni < 4; ni++)
    bv0[ni] = *(const bf16x8*)(smem + bB0 + (uint32_t)(ni*2048));

  #pragma unroll 1
  for(int s = 0; s < 74; s++){
    const int rdx  = (s < 72) ? (s % 3) : 0;
    const int gbuf = (s < 72) ? ((s/3) & 1) : (s - 72);
    const uint32_t baseA0 = ((rdx == 0) ? bA0_0 : (rdx == 1) ? bA0_1 : bA0_2)
                          + (uint32_t)gbuf*32768u;
    const uint32_t baseA1 = baseA0 ^ 64u;
    const uint32_t baseB0 = bB0 + (uint32_t)(s % 3)*32768u;
    const uint32_t baseB1 = baseB0 ^ 64u;

    // ---- ph0: read avY(r0-3,kc1)+bv1; issue staging; MFMA(avX,bv0)->acc[0..3] ----
    #pragma unroll
    for(int mi = 0; mi < 4; mi++)
      avY[mi] = *(const bf16x8*)(smem + baseA1 + (uint32_t)(mi*2048));
    #pragma unroll
    for(int ni = 0; ni < 4; ni++)
      bv1[ni] = *(const bf16x8*)(smem + baseB1 + (uint32_t)(ni*2048));
    if(s < 72) stB(s + 2, (s + 2) % 3);
    if(rdx == 0 && s < 73) stA_next(s);
    __builtin_amdgcn_s_setprio(1);
    #pragma unroll
    for(int ni = 0; ni < 4; ni++)
      #pragma unroll
      for(int mi = 0; mi < 4; mi++)
        acc[mi][ni] = __builtin_amdgcn_mfma_f32_16x16x32_bf16(avX[mi], bv0[ni], acc[mi][ni], 0, 0, 0);
    __builtin_amdgcn_s_setprio(0);

    // ---- ph1: read avX(r4-6,kc0); MFMA(avY,bv1)->acc[0..3] ----
    #pragma unroll
    for(int mi = 0; mi < 3; mi++)
      avX[mi] = *(const bf16x8*)(smem + baseA0 + (uint32_t)((mi + 4)*2048));
    __builtin_amdgcn_s_setprio(1);
    #pragma unroll
    for(int ni = 0; ni < 4; ni++)
      #pragma unroll
      for(int mi = 0; mi < 4; mi++)
        acc[mi][ni] = __builtin_amdgcn_mfma_f32_16x16x32_bf16(avY[mi], bv1[ni], acc[mi][ni], 0, 0, 0);
    __builtin_amdgcn_s_setprio(0);

    // ---- ph2: read avY(r4-6,kc1); MFMA(avX[0..2],bv0)->acc[4..6]; vmcnt(N)+bar ----
    #pragma unroll
    for(int mi = 0; mi < 3; mi++)
      avY[mi] = *(const bf16x8*)(smem + baseA1 + (uint32_t)((mi + 4)*2048));
    __builtin_amdgcn_s_setprio(1);
    #pragma unroll
    for(int ni = 0; ni < 4; ni++)
      #pragma unroll
      for(int mi = 0; mi < 3; mi++)
        acc[mi+4][ni] = __builtin_amdgcn_mfma_f32_16x16x32_bf16(avX[mi], bv0[ni], acc[mi+4][ni], 0, 0, 0);
    __builtin_amdgcn_s_setprio(0);
    if(rdx == 0){
      if(s < 72) asm volatile("s_waitcnt vmcnt(8)" ::: "memory");
      else       asm volatile("s_waitcnt vmcnt(0)" ::: "memory");
    } else {
      asm volatile("s_waitcnt vmcnt(4)" ::: "memory");
    }
    bar();     // the ONLY barrier per step

    // ---- ph3: read-ahead next step's avX,bv0; MFMA(avY[0..2],bv1)->acc[4..6] ----
    if(s < 73){
      const int s1 = s + 1;
      const int rdx1  = (s1 < 72) ? (s1 % 3) : 0;
      const int gbuf1 = (s1 < 72) ? ((s1/3) & 1) : (s1 - 72);
      const uint32_t baseA0n = ((rdx1 == 0) ? bA0_0 : (rdx1 == 1) ? bA0_1 : bA0_2)
                             + (uint32_t)gbuf1*32768u;
      const uint32_t baseB0n = bB0 + (uint32_t)(s1 % 3)*32768u;
      #pragma unroll
      for(int mi = 0; mi < 4; mi++)
        avX[mi] = *(const bf16x8*)(smem + baseA0n + (uint32_t)(mi*2048));
      #pragma unroll
      for(int ni = 0; ni < 4; ni++)
        bv0[ni] = *(const bf16x8*)(smem + baseB0n + (uint32_t)(ni*2048));
    }
    __builtin_amdgcn_s_setprio(1);
    #pragma unroll
    for(int ni = 0; ni < 4; ni++)
      #pragma unroll
      for(int mi = 0; mi < 3; mi++)
        acc[mi+4][ni] = __builtin_amdgcn_mfma_f32_16x16x32_bf16(avY[mi], bv1[ni], acc[mi+4][ni], 0, 0, 0);
    __builtin_amdgcn_s_setprio(0);
    // (no end-ph3 barrier — wave skew allowed up to next step's end-ph2)
  }

  // --- stage W2 (fp32 -> bf16) into LDS @W2_OFF, 512B rows, XOR-swizzled ---
  for(int e2 = tid; e2 < 48*256; e2 += 512){
    int row = e2 >> 8, k = e2 & 255;
    float f = (row < 36) ? w2[row*256 + k] : 0.f;
    uint32_t phys = ((uint32_t)(row*512 + k*2)) ^ (((uint32_t)(row & 7)) << 4);
    *(ushort_t*)(smem + W2_OFF + phys) = bf16r(f);
  }

  // --- epilogue: two passes of 112 pixels each ---
  #pragma unroll
  for(int pass = 0; pass < 2; pass++){
    if(pass) bar();
    if(wave_m == pass){
      #pragma unroll
      for(int ni = 0; ni < 4; ni++){
        int co = wave_n*64 + ni*16 + (l & 15);
        float bb1 = b1[co];
        float pp = pw[co];
        #pragma unroll
        for(int mi = 0; mi < 7; mi++){
          #pragma unroll
          for(int j = 0; j < 4; j++){
            float v = acc[mi][ni][j] + bb1;
            v = (v < 0.f) ? v*pp : v;
            int px = mi*16 + ((l >> 4) << 2) + j;     // 0..111
            uint32_t phys = ((uint32_t)(px*512 + co*2)) ^ (((uint32_t)(px & 7)) << 4);
            *(ushort_t*)(smem + phys) = bf16r(v);
          }
        }
      }
    }
    bar_lds();

    // mask GEMM: waves 0-6 -> px rows [16w,16w+16), N=48 (36 valid), K=256
    f32x4 acc2[3];
    #pragma unroll
    for(int ni = 0; ni < 3; ni++) acc2[ni] = zero4;
    if(w < 7){
      const uint32_t rowX = ((uint32_t)(16*w + (l & 15)))*512u;
      #pragma unroll
      for(int kq = 0; kq < 8; kq++){
        bf16x8 avx = *(const bf16x8*)(smem + ((rowX + (uint32_t)(kq*64) + koff) ^ swB));
        #pragma unroll
        for(int ni = 0; ni < 3; ni++){
          uint32_t rowW = ((uint32_t)(ni*16 + (l & 15)))*512u;
          bf16x8 bvx = *(const bf16x8*)(smem + W2_OFF + ((rowW + (uint32_t)(kq*64) + koff) ^ swB));
          acc2[ni] = __builtin_amdgcn_mfma_f32_16x16x32_bf16(avx, bvx, acc2[ni], 0, 0, 0);
        }
      }
    }
    bar_lds();   // all x reads done before mask overwrites smem regions
    if(w < 7){
      float* ml = (float*)(smem + MASK_OFF);
      #pragma unroll
      for(int ni = 0; ni < 3; ni++){
        int co2 = ni*16 + (l & 15);
        float bb2 = b2[co2 < 36 ? co2 : 35];
        #pragma unroll
        for(int j = 0; j < 4; j++){
          int px = 16*w + ((l >> 4) << 2) + j;
          ml[px*48 + co2] = acc2[ni][j] + bb2;
        }
      }
    }
    bar_lds();

    // softmax(2x18) + unfold-merge, 4 threads per pixel (112 px/pass -> 448 tasks)
    if(tid < 448){
      int px = tid >> 2;
      int hh = (tid >> 1) & 1;
      int c  = tid & 1;
      const float* ml = (const float*)(smem + MASK_OFF) + px*48 + hh*18;
      float mx = ml[0];
      #pragma unroll
      for(int k = 1; k < 18; k++) mx = fmaxf(mx, ml[k]);
      float e[18]; float sum = 0.f;
      #pragma unroll
      for(int k = 0; k < 18; k++){ e[k] = __expf(ml[k] - mx); sum += e[k]; }
      float inv = 1.f / sum;
      int x = x0 + pass*112 + px;
      int y = y0;
      const float* fi = init_flow + (size_t)(b*4 + 2*hh + c)*NPIX;
      const float* ff = flow_fix  + (size_t)(b*4 + 2*hh + c)*NPIX;
      float o = 0.f;
      #pragma unroll
      for(int s = 0; s < 9; s++){
        int yy = y + (s/3) - 1, xx = x + (s%3) - 1;
        if(yy >= 0 && yy < H_ && xx >= 0 && xx < W_){
          int idx = yy*W_ + xx;
          o += e[s]*fi[idx] + e[9+s]*ff[idx];
        }
      }
      out[(size_t)((b + 2*hh)*2 + c)*NPIX + y*W_ + x] = o * inv;
    }
  }
}

// ---------------- launcher ----------------
extern "C" void kernel_launch(void* const* d_in, const int* in_sizes, int n_in,
                              void* d_out, int out_size, void* d_ws, size_t ws_size,
                              hipStream_t stream) {
  const float* feature   = (const float*)d_in[0];
  const float* init_flow = (const float*)d_in[1];
  const float* flow_fix  = (const float*)d_in[2];
  const float* w1        = (const float*)d_in[3];
  const float* b1        = (const float*)d_in[4];
  const float* prelu_w   = (const float*)d_in[5];
  const float* w2        = (const float*)d_in[6];
  const float* b2        = (const float*)d_in[7];
  float* out = (float*)d_out;
  uint8_t* ws = (uint8_t*)d_ws;

  if(ws_size < WS_NEEDED) return;  // insufficient workspace -> fail visibly

  prep_x<<<64*2*HP_, 256, 0, stream>>>(feature, ws);
  prep_f<<<2*HP_,    256, 0, stream>>>(init_flow, flow_fix, ws);
  prep_w<<<4736,     256, 0, stream>>>(w1, ws);
  mega<<<1024, 512, 0, stream>>>(ws, w2, b1, prelu_w, b2, init_flow, flow_fix, out);
}